// Round 18
// baseline (718.841 us; speedup 1.0000x reference)
//
#include <hip/hip_runtime.h>
#include <math.h>

#define NNODES 50000
#define E0 800000
#define ETOT 850000
#define IN_DIM 1024
#define HEADS 4
#define C1 256      // HEADS*HID
#define C2 128      // OUT_DIM
#define NEG_SLOPE 0.2f

typedef short bf16x8 __attribute__((ext_vector_type(8)));
typedef float f32x4 __attribute__((ext_vector_type(4)));
typedef unsigned short ushort_t;

// ---------- helpers ----------
// NOTE: harness delivers integer inputs as int32 (verified round 1: int* passed,
// long long* faulted). Do NOT read edge_index as int64.
__device__ __forceinline__ void edge_sd(const int* __restrict__ ei, int e, int& s, int& d) {
    if (e < E0) { s = ei[e]; d = ei[E0 + e]; }
    else        { s = e - E0; d = s; }
}

__device__ __forceinline__ ushort_t f2b(float f) {   // f32 -> bf16 RNE
    unsigned u = __float_as_uint(f);
    return (ushort_t)((u + 0x7fffu + ((u >> 16) & 1u)) >> 16);
}
__device__ __forceinline__ float bf2f(ushort_t u) {
    return __uint_as_float((unsigned)u << 16);
}
__device__ __forceinline__ float lrelu(float v) { return v > 0.f ? v : NEG_SLOPE * v; }

__device__ __forceinline__ bf16x8 cvt_bf8(float4 f0, float4 f1) {
    bf16x8 p;
    p[0] = f2b(f0.x); p[1] = f2b(f0.y); p[2] = f2b(f0.z); p[3] = f2b(f0.w);
    p[4] = f2b(f1.x); p[5] = f2b(f1.y); p[6] = f2b(f1.z); p[7] = f2b(f1.w);
    return p;
}

// ---------- weight cast to BLOCKED bf16 layout: W[K][N] f32 -> WT[k/8][N][8] ----------
__global__ __launch_bounds__(256) void wtrans_kernel(const float* __restrict__ W,
                                                     ushort_t* __restrict__ WT,
                                                     int K, int N)
{
    int idx = blockIdx.x * 256 + threadIdx.x;
    if (idx >= K * N) return;
    int k = idx / N, n = idx % N;
    WT[((size_t)(k >> 3) * N + n) * 8 + (k & 7)] = f2b(W[idx]);
}

// ---------- MFMA GEMM, barrier-free, 16x64 PER WAVE (half the per-wave serial
// chain of R17's 32x64; 2x the waves). Block = 32 rows x 128 cols, 4 waves:
// wave w -> rows (w>>1)*16, cols (w&1)*64. Grid (N/128, M/32) = 3128 blocks /
// 12512 waves; 2 col-groups keep FETCH at 1xA (intra-block dup -> L1).
// A+B 2-deep reg prefetch throughout.
__global__ __launch_bounds__(256, 8) void gemm_fb(const float* __restrict__ A,
                                                  const ushort_t* __restrict__ Bblk,
                                                  ushort_t* __restrict__ Cb,
                                                  int M, int N, int K)
{
    const int tid  = threadIdx.x;
    const int lane = tid & 63;
    const int wid  = tid >> 6;
    const int rowBase = blockIdx.y * 32 + (wid >> 1) * 16;
    const int colBase = blockIdx.x * 128 + (wid & 1) * 64;
    const int r0 = lane & 15;
    const int kh = lane >> 4;

    const float* aP0 = A + (size_t)min(rowBase + r0, M - 1) * K + kh * 8;
    const ushort_t* bP = Bblk + ((size_t)kh * N + colBase + r0) * 8;
    const size_t bStep = (size_t)4 * N * 8;   // k-plane advance per k-step(32)

    f32x4 zero = {0.f, 0.f, 0.f, 0.f};
    f32x4 acc[4];
    #pragma unroll
    for (int j = 0; j < 4; ++j) acc[j] = zero;

    float4 sa[2], sb[2];                      // A prefetch sets
    bf16x8 bA[4], bB[4];                      // B prefetch sets
    sa[0] = *(const float4*)(aP0 + 0); sa[1] = *(const float4*)(aP0 + 4);
    #pragma unroll
    for (int fj = 0; fj < 4; ++fj) bA[fj] = *(const bf16x8*)(bP + fj * 128);

    const int nt = K >> 5;                    // 32 for K=1024 (even)
    for (int t = 0; t < nt; t += 2) {
        // ---- even: prefetch t+1 (A->sb, B->bB), compute t from sa/bA ----
        {
            const int kt1 = (t + 1) << 5;
            sb[0] = *(const float4*)(aP0 + kt1 + 0); sb[1] = *(const float4*)(aP0 + kt1 + 4);
            const ushort_t* bb = bP + (size_t)(t + 1) * bStep;
            #pragma unroll
            for (int fj = 0; fj < 4; ++fj) bB[fj] = *(const bf16x8*)(bb + fj * 128);

            bf16x8 aF0 = cvt_bf8(sa[0], sa[1]);
            #pragma unroll
            for (int fj = 0; fj < 4; ++fj)
                acc[fj] = __builtin_amdgcn_mfma_f32_16x16x32_bf16(aF0, bA[fj], acc[fj], 0, 0, 0);
        }
        // ---- odd: prefetch t+2 (A->sa, B->bA), compute t+1 from sb/bB ----
        {
            const bool has2 = (t + 2) < nt;
            if (has2) {
                const int kt2 = (t + 2) << 5;
                sa[0] = *(const float4*)(aP0 + kt2 + 0); sa[1] = *(const float4*)(aP0 + kt2 + 4);
                const ushort_t* bb = bP + (size_t)(t + 2) * bStep;
                #pragma unroll
                for (int fj = 0; fj < 4; ++fj) bA[fj] = *(const bf16x8*)(bb + fj * 128);
            }
            bf16x8 aF0 = cvt_bf8(sb[0], sb[1]);
            #pragma unroll
            for (int fj = 0; fj < 4; ++fj)
                acc[fj] = __builtin_amdgcn_mfma_f32_16x16x32_bf16(aF0, bB[fj], acc[fj], 0, 0, 0);
        }
    }

    // C/D layout (m89-verified): col = lane&15, row = (lane>>4)*4 + reg
    {
        int row0 = rowBase + kh * 4;
        #pragma unroll
        for (int i = 0; i < 4; ++i) {
            int row = row0 + i;
            if (row < M) {
                #pragma unroll
                for (int fj = 0; fj < 4; ++fj)
                    Cb[(size_t)row * N + colBase + fj * 16 + r0] = f2b(acc[fj][i]);
            }
        }
    }
}

// ---------- same 16x64/wave structure, A already bf16 ----------
__global__ __launch_bounds__(256, 8) void gemm_bb(const ushort_t* __restrict__ Ab,
                                                  const ushort_t* __restrict__ Bblk,
                                                  ushort_t* __restrict__ Cb,
                                                  int M, int N, int K)
{
    const int tid  = threadIdx.x;
    const int lane = tid & 63;
    const int wid  = tid >> 6;
    const int rowBase = blockIdx.y * 32 + (wid >> 1) * 16;
    const int colBase = blockIdx.x * 128 + (wid & 1) * 64;
    const int r0 = lane & 15;
    const int kh = lane >> 4;

    const ushort_t* aP0 = Ab + (size_t)min(rowBase + r0, M - 1) * K + kh * 8;
    const ushort_t* bP = Bblk + ((size_t)kh * N + colBase + r0) * 8;
    const size_t bStep = (size_t)4 * N * 8;

    f32x4 zero = {0.f, 0.f, 0.f, 0.f};
    f32x4 acc[4];
    #pragma unroll
    for (int j = 0; j < 4; ++j) acc[j] = zero;

    bf16x8 sa0, sb0;
    bf16x8 bA[4], bB[4];
    sa0 = *(const bf16x8*)(aP0);
    #pragma unroll
    for (int fj = 0; fj < 4; ++fj) bA[fj] = *(const bf16x8*)(bP + fj * 128);

    const int nt = K >> 5;                    // 8 for K=256 (even)
    for (int t = 0; t < nt; t += 2) {
        {
            const int kt1 = (t + 1) << 5;
            sb0 = *(const bf16x8*)(aP0 + kt1);
            const ushort_t* bb = bP + (size_t)(t + 1) * bStep;
            #pragma unroll
            for (int fj = 0; fj < 4; ++fj) bB[fj] = *(const bf16x8*)(bb + fj * 128);
            #pragma unroll
            for (int fj = 0; fj < 4; ++fj)
                acc[fj] = __builtin_amdgcn_mfma_f32_16x16x32_bf16(sa0, bA[fj], acc[fj], 0, 0, 0);
        }
        {
            const bool has2 = (t + 2) < nt;
            if (has2) {
                const int kt2 = (t + 2) << 5;
                sa0 = *(const bf16x8*)(aP0 + kt2);
                const ushort_t* bb = bP + (size_t)(t + 2) * bStep;
                #pragma unroll
                for (int fj = 0; fj < 4; ++fj) bA[fj] = *(const bf16x8*)(bb + fj * 128);
            }
            #pragma unroll
            for (int fj = 0; fj < 4; ++fj)
                acc[fj] = __builtin_amdgcn_mfma_f32_16x16x32_bf16(sb0, bB[fj], acc[fj], 0, 0, 0);
        }
    }

    {
        int row0 = rowBase + kh * 4;
        #pragma unroll
        for (int i = 0; i < 4; ++i) {
            int row = row0 + i;
            if (row < M) {
                #pragma unroll
                for (int fj = 0; fj < 4; ++fj)
                    Cb[(size_t)row * N + colBase + fj * 16 + r0] = f2b(acc[fj][i]);
            }
        }
    }
}

// ---------- per-node attention halves, layer 1 (bf16 h1) ----------
__global__ __launch_bounds__(256) void alpha1_kernel(const ushort_t* __restrict__ h1b,
                                                     const float* __restrict__ asrc,
                                                     const float* __restrict__ adst,
                                                     float* __restrict__ out_s,
                                                     float* __restrict__ out_d)
{
    int n = blockIdx.x;
    int t = threadIdx.x;
    float h = bf2f(h1b[(size_t)n * C1 + t]);
    float s = h * asrc[t];
    float d = h * adst[t];
    #pragma unroll
    for (int off = 32; off > 0; off >>= 1) {
        s += __shfl_down(s, off);
        d += __shfl_down(d, off);
    }
    if ((t & 63) == 0) {
        out_s[n * HEADS + (t >> 6)] = s;
        out_d[n * HEADS + (t >> 6)] = d;
    }
}

// ---------- per-node attention halves, layer 2 (bf16 h2) ----------
__global__ __launch_bounds__(64) void alpha2_kernel(const ushort_t* __restrict__ h2b,
                                                    const float* __restrict__ asrc,
                                                    const float* __restrict__ adst,
                                                    float* __restrict__ out_s,
                                                    float* __restrict__ out_d)
{
    int n = blockIdx.x;
    int t = threadIdx.x;
    float a = bf2f(h2b[(size_t)n * C2 + t]);
    float b = bf2f(h2b[(size_t)n * C2 + t + 64]);
    float s = a * asrc[t] + b * asrc[t + 64];
    float d = a * adst[t] + b * adst[t + 64];
    #pragma unroll
    for (int off = 32; off > 0; off >>= 1) {
        s += __shfl_down(s, off);
        d += __shfl_down(d, off);
    }
    if (t == 0) { out_s[n] = s; out_d[n] = d; }
}

// ---------- CSR build ----------
__global__ __launch_bounds__(256) void deg_kernel(const int* __restrict__ ei,
                                                  int* __restrict__ deg)
{
    int e = blockIdx.x * blockDim.x + threadIdx.x;
    if (e >= ETOT) return;
    int s, d; edge_sd(ei, e, s, d);
    atomicAdd(&deg[d], 1);
}

// 4 elems/thread + wave shfl scan.
#define SCAN_T 1024
__global__ __launch_bounds__(SCAN_T) void scan_kernel(const int* __restrict__ deg,
                                                      int* __restrict__ rowptr)
{
    __shared__ int wsum[16];
    __shared__ int chunk_tot;
    __shared__ int carry_s;
    const int t = threadIdx.x, lane = t & 63, w = t >> 6;
    if (t == 0) carry_s = 0;
    __syncthreads();
    for (int base = 0; base < NNODES; base += SCAN_T * 4) {
        int idx = base + t * 4;
        int v0 = (idx + 0 < NNODES) ? deg[idx + 0] : 0;
        int v1 = (idx + 1 < NNODES) ? deg[idx + 1] : 0;
        int v2 = (idx + 2 < NNODES) ? deg[idx + 2] : 0;
        int v3 = (idx + 3 < NNODES) ? deg[idx + 3] : 0;
        int p0 = v0, p1 = p0 + v1, p2 = p1 + v2, p3 = p2 + v3;
        int incl = p3;
        #pragma unroll
        for (int off = 1; off < 64; off <<= 1) {
            int nb = __shfl_up(incl, off);
            if (lane >= off) incl += nb;
        }
        if (lane == 63) wsum[w] = incl;
        __syncthreads();
        if (w == 0 && lane < 16) {
            int ws = wsum[lane];
            int wincl = ws;
            #pragma unroll
            for (int off = 1; off < 16; off <<= 1) {
                int nb = __shfl_up(wincl, off);
                if (lane >= off) wincl += nb;
            }
            wsum[lane] = wincl - ws;            // exclusive
            if (lane == 15) chunk_tot = wincl;
        }
        __syncthreads();
        int carry = carry_s;
        int basev = carry + wsum[w] + (incl - p3);
        if (idx + 0 < NNODES) rowptr[idx + 0] = basev;
        if (idx + 1 < NNODES) rowptr[idx + 1] = basev + p0;
        if (idx + 2 < NNODES) rowptr[idx + 2] = basev + p1;
        if (idx + 3 < NNODES) rowptr[idx + 3] = basev + p2;
        __syncthreads();
        if (t == 0) carry_s = carry + chunk_tot;
        __syncthreads();
    }
    if (threadIdx.x == 0) rowptr[NNODES] = carry_s;
}

__global__ __launch_bounds__(256) void scatter_kernel(const int* __restrict__ ei,
                                                      int* __restrict__ cursor,
                                                      int* __restrict__ srcs)
{
    int e = blockIdx.x * blockDim.x + threadIdx.x;
    if (e >= ETOT) return;
    int s, d; edge_sd(ei, e, s, d);
    int pos = atomicAdd(&cursor[d], 1);
    srcs[pos] = s;
}

// ---------- per-edge normalized attention weights, layer 1 (4 heads) ----------
__global__ __launch_bounds__(256) void weights1_kernel(const int* __restrict__ rowptr,
                                                       const int* __restrict__ srcs,
                                                       const float4* __restrict__ as1,
                                                       const float4* __restrict__ ad1,
                                                       float4* __restrict__ wbuf)
{
    int d = blockIdx.x * 4 + (threadIdx.x >> 6);
    if (d >= NNODES) return;
    int lane = threadIdx.x & 63;
    int beg = rowptr[d], end = rowptr[d + 1];
    float4 adv = ad1[d];
    float m0 = -INFINITY, m1 = -INFINITY, m2 = -INFINITY, m3 = -INFINITY;
    for (int i = beg + lane; i < end; i += 64) {
        int s = srcs[i];
        float4 av = as1[s];
        m0 = fmaxf(m0, lrelu(av.x + adv.x));
        m1 = fmaxf(m1, lrelu(av.y + adv.y));
        m2 = fmaxf(m2, lrelu(av.z + adv.z));
        m3 = fmaxf(m3, lrelu(av.w + adv.w));
    }
    #pragma unroll
    for (int off = 32; off > 0; off >>= 1) {
        m0 = fmaxf(m0, __shfl_xor(m0, off));
        m1 = fmaxf(m1, __shfl_xor(m1, off));
        m2 = fmaxf(m2, __shfl_xor(m2, off));
        m3 = fmaxf(m3, __shfl_xor(m3, off));
    }
    float s0 = 0.f, s1 = 0.f, s2 = 0.f, s3 = 0.f;
    for (int i = beg + lane; i < end; i += 64) {
        int s = srcs[i];
        float4 av = as1[s];
        float w0 = expf(lrelu(av.x + adv.x) - m0);
        float w1 = expf(lrelu(av.y + adv.y) - m1);
        float w2 = expf(lrelu(av.z + adv.z) - m2);
        float w3 = expf(lrelu(av.w + adv.w) - m3);
        wbuf[i] = make_float4(w0, w1, w2, w3);
        s0 += w0; s1 += w1; s2 += w2; s3 += w3;
    }
    #pragma unroll
    for (int off = 32; off > 0; off >>= 1) {
        s0 += __shfl_xor(s0, off);
        s1 += __shfl_xor(s1, off);
        s2 += __shfl_xor(s2, off);
        s3 += __shfl_xor(s3, off);
    }
    float i0 = 1.f / (s0 + 1e-16f), i1 = 1.f / (s1 + 1e-16f);
    float i2 = 1.f / (s2 + 1e-16f), i3 = 1.f / (s3 + 1e-16f);
    for (int i = beg + lane; i < end; i += 64) {
        float4 wv = wbuf[i];
        wbuf[i] = make_float4(wv.x * i0, wv.y * i1, wv.z * i2, wv.w * i3);
    }
}

// ---------- per-edge normalized attention weights, layer 2 (1 head) ----------
__global__ __launch_bounds__(256) void weights2_kernel(const int* __restrict__ rowptr,
                                                       const int* __restrict__ srcs,
                                                       const float* __restrict__ as2,
                                                       const float* __restrict__ ad2,
                                                       float* __restrict__ wbuf)
{
    int d = blockIdx.x * 4 + (threadIdx.x >> 6);
    if (d >= NNODES) return;
    int lane = threadIdx.x & 63;
    int beg = rowptr[d], end = rowptr[d + 1];
    float adv = ad2[d];
    float m = -INFINITY;
    for (int i = beg + lane; i < end; i += 64)
        m = fmaxf(m, lrelu(as2[srcs[i]] + adv));
    #pragma unroll
    for (int off = 32; off > 0; off >>= 1) m = fmaxf(m, __shfl_xor(m, off));
    float sm = 0.f;
    for (int i = beg + lane; i < end; i += 64) {
        float w = expf(lrelu(as2[srcs[i]] + adv) - m);
        wbuf[i] = w;
        sm += w;
    }
    #pragma unroll
    for (int off = 32; off > 0; off >>= 1) sm += __shfl_xor(sm, off);
    float inv = 1.f / (sm + 1e-16f);
    for (int i = beg + lane; i < end; i += 64) wbuf[i] *= inv;
}

// ---------- layer-1 aggregation: wave per dst, lane = 4 channels, 8x unrolled ----------
__global__ __launch_bounds__(256) void aggr1_csr(const int* __restrict__ rowptr,
                                                 const int* __restrict__ srcs,
                                                 const ushort_t* __restrict__ h1b,
                                                 const float* __restrict__ wbuf,
                                                 const float* __restrict__ b1,
                                                 ushort_t* __restrict__ out)
{
    int d = blockIdx.x * 4 + (threadIdx.x >> 6);
    if (d >= NNODES) return;
    int lane = threadIdx.x & 63;
    int c0 = lane * 4;                 // channels [c0, c0+4)
    int head = lane >> 4;              // c0>>6
    int beg = rowptr[d], end = rowptr[d + 1];
    float a0 = 0.f, a1 = 0.f, a2 = 0.f, a3 = 0.f;
    int i = beg;
    for (; i + 7 < end; i += 8) {
        int s_[8];
        float w_[8];
        ushort4 v_[8];
        #pragma unroll
        for (int u = 0; u < 8; ++u) {
            s_[u] = srcs[i + u];
            w_[u] = wbuf[(i + u) * 4 + head];
        }
        #pragma unroll
        for (int u = 0; u < 8; ++u)
            v_[u] = *(const ushort4*)(h1b + (size_t)s_[u] * C1 + c0);
        #pragma unroll
        for (int u = 0; u < 8; ++u) {
            a0 = fmaf(w_[u], bf2f(v_[u].x), a0);
            a1 = fmaf(w_[u], bf2f(v_[u].y), a1);
            a2 = fmaf(w_[u], bf2f(v_[u].z), a2);
            a3 = fmaf(w_[u], bf2f(v_[u].w), a3);
        }
    }
    for (; i < end; ++i) {
        int s0 = srcs[i];
        float w0 = wbuf[i * 4 + head];
        ushort4 v0 = *(const ushort4*)(h1b + (size_t)s0 * C1 + c0);
        a0 = fmaf(w0, bf2f(v0.x), a0); a1 = fmaf(w0, bf2f(v0.y), a1);
        a2 = fmaf(w0, bf2f(v0.z), a2); a3 = fmaf(w0, bf2f(v0.w), a3);
    }
    float4 bv = *(const float4*)(b1 + c0);
    float o0 = a0 + bv.x, o1 = a1 + bv.y, o2 = a2 + bv.z, o3 = a3 + bv.w;
    ushort4 r;
    r.x = f2b(o0 > 0.f ? o0 : (expf(o0) - 1.f));
    r.y = f2b(o1 > 0.f ? o1 : (expf(o1) - 1.f));
    r.z = f2b(o2 > 0.f ? o2 : (expf(o2) - 1.f));
    r.w = f2b(o3 > 0.f ? o3 : (expf(o3) - 1.f));
    *(ushort4*)(out + (size_t)d * C1 + c0) = r;
}

// ---------- layer-2 aggregation: wave per dst, lane = 2 channels, 8x unrolled ----------
__global__ __launch_bounds__(256) void aggr2_csr(const int* __restrict__ rowptr,
                                                 const int* __restrict__ srcs,
                                                 const ushort_t* __restrict__ h2b,
                                                 const float* __restrict__ wbuf,
                                                 const float* __restrict__ b2,
                                                 float* __restrict__ out)
{
    int d = blockIdx.x * 4 + (threadIdx.x >> 6);
    if (d >= NNODES) return;
    int lane = threadIdx.x & 63;
    int c0 = lane * 2;
    int beg = rowptr[d], end = rowptr[d + 1];
    float a0 = 0.f, a1 = 0.f;
    int i = beg;
    for (; i + 7 < end; i += 8) {
        int s_[8];
        float w_[8];
        ushort2 v_[8];
        #pragma unroll
        for (int u = 0; u < 8; ++u) {
            s_[u] = srcs[i + u];
            w_[u] = wbuf[i + u];
        }
        #pragma unroll
        for (int u = 0; u < 8; ++u)
            v_[u] = *(const ushort2*)(h2b + (size_t)s_[u] * C2 + c0);
        #pragma unroll
        for (int u = 0; u < 8; ++u) {
            a0 = fmaf(w_[u], bf2f(v_[u].x), a0);
            a1 = fmaf(w_[u], bf2f(v_[u].y), a1);
        }
    }
    for (; i < end; ++i) {
        float w0 = wbuf[i];
        ushort2 v0 = *(const ushort2*)(h2b + (size_t)srcs[i] * C2 + c0);
        a0 = fmaf(w0, bf2f(v0.x), a0); a1 = fmaf(w0, bf2f(v0.y), a1);
    }
    float2 bv = *(const float2*)(b2 + c0);
    float o0 = a0 + bv.x, o1 = a1 + bv.y;
    float sq = o0 * o0 + o1 * o1;
    #pragma unroll
    for (int off = 32; off > 0; off >>= 1) sq += __shfl_xor(sq, off);
    float inv = 1.0f / fmaxf(sqrtf(sq), 1e-12f);
    float2 r = make_float2(o0 * inv, o1 * inv);
    *(float2*)(out + (size_t)d * C2 + c0) = r;
}

extern "C" void kernel_launch(void* const* d_in, const int* in_sizes, int n_in,
                              void* d_out, int out_size, void* d_ws, size_t ws_size,
                              hipStream_t stream)
{
    const float* x     = (const float*)d_in[0];
    const int*   ei    = (const int*)d_in[1];
    const float* W1    = (const float*)d_in[2];
    const float* asrc1 = (const float*)d_in[3];
    const float* adst1 = (const float*)d_in[4];
    const float* b1    = (const float*)d_in[5];
    const float* W2    = (const float*)d_in[6];
    const float* asrc2 = (const float*)d_in[7];
    const float* adst2 = (const float*)d_in[8];
    const float* b2    = (const float*)d_in[9];
    float* out = (float*)d_out;

    char* ws = (char*)d_ws;
    size_t off = 0;
    auto alloc = [&](size_t nbytes) {
        void* p = ws + off;
        off += (nbytes + 15) & ~(size_t)15;
        return p;
    };
    ushort_t* h1b    = (ushort_t*)alloc((size_t)NNODES * C1 * 2);   // 25.6 MB
    ushort_t* act1b  = (ushort_t*)alloc((size_t)NNODES * C1 * 2);   // 25.6 MB
    ushort_t* h2b    = (ushort_t*)alloc((size_t)NNODES * C2 * 2);   // 12.8 MB
    ushort_t* W1blk  = (ushort_t*)alloc((size_t)C1 * IN_DIM * 2);
    ushort_t* W2blk  = (ushort_t*)alloc((size_t)C2 * C1 * 2);
    float*    as1    = (float*)alloc((size_t)NNODES * HEADS * 4);
    float*    ad1    = (float*)alloc((size_t)NNODES * HEADS * 4);
    float*    as2    = (float*)alloc((size_t)NNODES * 4);
    float*    ad2    = (float*)alloc((size_t)NNODES * 4);
    float*    wbuf1  = (float*)alloc((size_t)ETOT * HEADS * 4);     // 13.6 MB
    float*    wbuf2  = (float*)alloc((size_t)ETOT * 4);             // 3.4 MB
    int*      deg    = (int*)alloc((size_t)NNODES * 4);
    int*      rowptr = (int*)alloc((size_t)(NNODES + 1) * 4);
    int*      cursor = (int*)alloc((size_t)(NNODES + 1) * 4);
    int*      srcs   = (int*)alloc((size_t)ETOT * 4);               // 3.4 MB

    const int eb = (ETOT + 255) / 256;
    const int nb4 = (NNODES + 3) / 4;
    const int rb32 = (NNODES + 31) / 32;

    // ---- weight prep (blocked bf16 layout) ----
    wtrans_kernel<<<(IN_DIM * C1 + 255) / 256, 256, 0, stream>>>(W1, W1blk, IN_DIM, C1);
    wtrans_kernel<<<(C1 * C2 + 255) / 256, 256, 0, stream>>>(W2, W2blk, C1, C2);

    // ---- CSR build ----
    hipMemsetAsync(deg, 0, (size_t)NNODES * 4, stream);
    deg_kernel<<<eb, 256, 0, stream>>>(ei, deg);
    scan_kernel<<<1, SCAN_T, 0, stream>>>(deg, rowptr);
    hipMemcpyAsync(cursor, rowptr, (size_t)(NNODES + 1) * 4, hipMemcpyDeviceToDevice, stream);
    scatter_kernel<<<eb, 256, 0, stream>>>(ei, cursor, srcs);

    // ---- Layer 1 ----
    dim3 g1(C1 / 128, rb32);   // 2 col-groups x 1563 row-blocks = 3126 blocks
    gemm_fb<<<g1, 256, 0, stream>>>(x, W1blk, h1b, NNODES, C1, IN_DIM);
    alpha1_kernel<<<NNODES, 256, 0, stream>>>(h1b, asrc1, adst1, as1, ad1);
    weights1_kernel<<<nb4, 256, 0, stream>>>(rowptr, srcs, (const float4*)as1,
                                             (const float4*)ad1, (float4*)wbuf1);
    aggr1_csr<<<nb4, 256, 0, stream>>>(rowptr, srcs, h1b, wbuf1, b1, act1b);

    // ---- Layer 2 ----
    dim3 g2(C2 / 128, rb32);   // 1 col-group: A read exactly once
    gemm_bb<<<g2, 256, 0, stream>>>(act1b, W2blk, h2b, NNODES, C2, C1);
    alpha2_kernel<<<NNODES, 64, 0, stream>>>(h2b, asrc2, adst2, as2, ad2);
    weights2_kernel<<<nb4, 256, 0, stream>>>(rowptr, srcs, as2, ad2, wbuf2);
    aggr2_csr<<<nb4, 256, 0, stream>>>(rowptr, srcs, h2b, wbuf2, b2, out);
}

// Round 19
// 465.568 us; speedup vs baseline: 1.5440x; 1.5440x over previous
//
#include <hip/hip_runtime.h>
#include <math.h>

#define NNODES 50000
#define E0 800000
#define ETOT 850000
#define IN_DIM 1024
#define HEADS 4
#define C1 256      // HEADS*HID
#define C2 128      // OUT_DIM
#define NEG_SLOPE 0.2f

typedef short bf16x8 __attribute__((ext_vector_type(8)));
typedef float f32x4 __attribute__((ext_vector_type(4)));
typedef unsigned short ushort_t;

// ---------- helpers ----------
// NOTE: harness delivers integer inputs as int32 (verified round 1: int* passed,
// long long* faulted). Do NOT read edge_index as int64.
__device__ __forceinline__ void edge_sd(const int* __restrict__ ei, int e, int& s, int& d) {
    if (e < E0) { s = ei[e]; d = ei[E0 + e]; }
    else        { s = e - E0; d = s; }
}

__device__ __forceinline__ ushort_t f2b(float f) {   // f32 -> bf16 RNE
    unsigned u = __float_as_uint(f);
    return (ushort_t)((u + 0x7fffu + ((u >> 16) & 1u)) >> 16);
}
__device__ __forceinline__ float bf2f(ushort_t u) {
    return __uint_as_float((unsigned)u << 16);
}
__device__ __forceinline__ float lrelu(float v) { return v > 0.f ? v : NEG_SLOPE * v; }

__device__ __forceinline__ bf16x8 cvt_bf8(float4 f0, float4 f1) {
    bf16x8 p;
    p[0] = f2b(f0.x); p[1] = f2b(f0.y); p[2] = f2b(f0.z); p[3] = f2b(f0.w);
    p[4] = f2b(f1.x); p[5] = f2b(f1.y); p[6] = f2b(f1.z); p[7] = f2b(f1.w);
    return p;
}

// ---------- weight cast to BLOCKED bf16 layout: W[K][N] f32 -> WT[k/8][N][8] ----------
__global__ __launch_bounds__(256) void wtrans_kernel(const float* __restrict__ W,
                                                     ushort_t* __restrict__ WT,
                                                     int K, int N)
{
    int idx = blockIdx.x * 256 + threadIdx.x;
    if (idx >= K * N) return;
    int k = idx / N, n = idx % N;
    WT[((size_t)(k >> 3) * N + n) * 8 + (k & 7)] = f2b(W[idx]);
}

// ---------- MFMA GEMM, BARRIER-FREE: each wave owns a 32x128 output tile ----------
// Best-measured config (R12-proposal, 467us total). No LDS, no __syncthreads.
// A frags: global->reg 2-deep named-set prefetch. B frags: per-k-step from
// L2-hot blocked weights. Col-block = blockIdx.x (fastest) so duplicate
// A-readers are dispatch-adjacent -> L2/L3 dedup (FETCH = 1xA).
__global__ __launch_bounds__(256, 3) void gemm_fb(const float* __restrict__ A,
                                                  const ushort_t* __restrict__ Bblk,
                                                  ushort_t* __restrict__ Cb,
                                                  int M, int N, int K)
{
    const int tid  = threadIdx.x;
    const int lane = tid & 63;
    const int wid  = tid >> 6;
    const int rowBase = blockIdx.y * 128 + wid * 32;
    const int colBase = blockIdx.x * 128;
    const int r0 = lane & 15;
    const int kh = lane >> 4;

    const float* aP0 = A + (size_t)min(rowBase + r0,      M - 1) * K + kh * 8;
    const float* aP1 = A + (size_t)min(rowBase + 16 + r0, M - 1) * K + kh * 8;
    const ushort_t* bP = Bblk + ((size_t)kh * N + colBase + r0) * 8;
    const size_t bStep = (size_t)4 * N * 8;   // k-plane advance per k-step(32)

    f32x4 zero = {0.f, 0.f, 0.f, 0.f};
    f32x4 acc[2][8];
    #pragma unroll
    for (int i = 0; i < 2; ++i)
        #pragma unroll
        for (int j = 0; j < 8; ++j) acc[i][j] = zero;

    float4 sa[4], sb[4];                      // named 2-deep A prefetch sets
    sa[0] = *(const float4*)(aP0 + 0); sa[1] = *(const float4*)(aP0 + 4);
    sa[2] = *(const float4*)(aP1 + 0); sa[3] = *(const float4*)(aP1 + 4);

    const int nt = K >> 5;                    // 32 for K=1024 (even)
    for (int t = 0; t < nt; t += 2) {
        // ---- even step: compute from sa, prefetch t+1 into sb ----
        {
            const int kt1 = (t + 1) << 5;
            sb[0] = *(const float4*)(aP0 + kt1 + 0); sb[1] = *(const float4*)(aP0 + kt1 + 4);
            sb[2] = *(const float4*)(aP1 + kt1 + 0); sb[3] = *(const float4*)(aP1 + kt1 + 4);
            const ushort_t* bb = bP + (size_t)t * bStep;
            bf16x8 aF0 = cvt_bf8(sa[0], sa[1]);
            bf16x8 aF1 = cvt_bf8(sa[2], sa[3]);
            #pragma unroll
            for (int fj = 0; fj < 8; ++fj) {
                bf16x8 bF = *(const bf16x8*)(bb + fj * 128);
                acc[0][fj] = __builtin_amdgcn_mfma_f32_16x16x32_bf16(aF0, bF, acc[0][fj], 0, 0, 0);
                acc[1][fj] = __builtin_amdgcn_mfma_f32_16x16x32_bf16(aF1, bF, acc[1][fj], 0, 0, 0);
            }
        }
        // ---- odd step: compute from sb, prefetch t+2 into sa ----
        {
            const bool has2 = (t + 2) < nt;
            if (has2) {
                const int kt2 = (t + 2) << 5;
                sa[0] = *(const float4*)(aP0 + kt2 + 0); sa[1] = *(const float4*)(aP0 + kt2 + 4);
                sa[2] = *(const float4*)(aP1 + kt2 + 0); sa[3] = *(const float4*)(aP1 + kt2 + 4);
            }
            const ushort_t* bb = bP + (size_t)(t + 1) * bStep;
            bf16x8 aF0 = cvt_bf8(sb[0], sb[1]);
            bf16x8 aF1 = cvt_bf8(sb[2], sb[3]);
            #pragma unroll
            for (int fj = 0; fj < 8; ++fj) {
                bf16x8 bF = *(const bf16x8*)(bb + fj * 128);
                acc[0][fj] = __builtin_amdgcn_mfma_f32_16x16x32_bf16(aF0, bF, acc[0][fj], 0, 0, 0);
                acc[1][fj] = __builtin_amdgcn_mfma_f32_16x16x32_bf16(aF1, bF, acc[1][fj], 0, 0, 0);
            }
        }
    }

    // C/D layout (m89-verified): col = lane&15, row = (lane>>4)*4 + reg
    #pragma unroll
    for (int fi = 0; fi < 2; ++fi) {
        int row0 = rowBase + fi * 16 + kh * 4;
        #pragma unroll
        for (int i = 0; i < 4; ++i) {
            int row = row0 + i;
            if (row < M) {
                #pragma unroll
                for (int fj = 0; fj < 8; ++fj)
                    Cb[(size_t)row * N + colBase + fj * 16 + r0] = f2b(acc[fi][fj][i]);
            }
        }
    }
}

// ---------- same barrier-free structure, A already bf16, 32x128 per wave ----------
__global__ __launch_bounds__(256, 3) void gemm_bb(const ushort_t* __restrict__ Ab,
                                                  const ushort_t* __restrict__ Bblk,
                                                  ushort_t* __restrict__ Cb,
                                                  int M, int N, int K)
{
    const int tid  = threadIdx.x;
    const int lane = tid & 63;
    const int wid  = tid >> 6;
    const int rowBase = blockIdx.y * 128 + wid * 32;
    const int colBase = blockIdx.x * 128;
    const int r0 = lane & 15;
    const int kh = lane >> 4;

    const ushort_t* aP0 = Ab + (size_t)min(rowBase + r0,      M - 1) * K + kh * 8;
    const ushort_t* aP1 = Ab + (size_t)min(rowBase + 16 + r0, M - 1) * K + kh * 8;
    const ushort_t* bP = Bblk + ((size_t)kh * N + colBase + r0) * 8;
    const size_t bStep = (size_t)4 * N * 8;

    f32x4 zero = {0.f, 0.f, 0.f, 0.f};
    f32x4 acc[2][8];
    #pragma unroll
    for (int i = 0; i < 2; ++i)
        #pragma unroll
        for (int j = 0; j < 8; ++j) acc[i][j] = zero;

    bf16x8 sa0, sa1, sb0, sb1;
    sa0 = *(const bf16x8*)(aP0); sa1 = *(const bf16x8*)(aP1);

    const int nt = K >> 5;                    // 8 for K=256 (even)
    for (int t = 0; t < nt; t += 2) {
        {
            const int kt1 = (t + 1) << 5;
            sb0 = *(const bf16x8*)(aP0 + kt1); sb1 = *(const bf16x8*)(aP1 + kt1);
            const ushort_t* bb = bP + (size_t)t * bStep;
            #pragma unroll
            for (int fj = 0; fj < 8; ++fj) {
                bf16x8 bF = *(const bf16x8*)(bb + fj * 128);
                acc[0][fj] = __builtin_amdgcn_mfma_f32_16x16x32_bf16(sa0, bF, acc[0][fj], 0, 0, 0);
                acc[1][fj] = __builtin_amdgcn_mfma_f32_16x16x32_bf16(sa1, bF, acc[1][fj], 0, 0, 0);
            }
        }
        {
            const bool has2 = (t + 2) < nt;
            if (has2) {
                const int kt2 = (t + 2) << 5;
                sa0 = *(const bf16x8*)(aP0 + kt2); sa1 = *(const bf16x8*)(aP1 + kt2);
            }
            const ushort_t* bb = bP + (size_t)(t + 1) * bStep;
            #pragma unroll
            for (int fj = 0; fj < 8; ++fj) {
                bf16x8 bF = *(const bf16x8*)(bb + fj * 128);
                acc[0][fj] = __builtin_amdgcn_mfma_f32_16x16x32_bf16(sb0, bF, acc[0][fj], 0, 0, 0);
                acc[1][fj] = __builtin_amdgcn_mfma_f32_16x16x32_bf16(sb1, bF, acc[1][fj], 0, 0, 0);
            }
        }
    }

    #pragma unroll
    for (int fi = 0; fi < 2; ++fi) {
        int row0 = rowBase + fi * 16 + kh * 4;
        #pragma unroll
        for (int i = 0; i < 4; ++i) {
            int row = row0 + i;
            if (row < M) {
                #pragma unroll
                for (int fj = 0; fj < 8; ++fj)
                    Cb[(size_t)row * N + colBase + fj * 16 + r0] = f2b(acc[fi][fj][i]);
            }
        }
    }
}

// ---------- per-node attention halves, layer 1 (bf16 h1) ----------
__global__ __launch_bounds__(256) void alpha1_kernel(const ushort_t* __restrict__ h1b,
                                                     const float* __restrict__ asrc,
                                                     const float* __restrict__ adst,
                                                     float* __restrict__ out_s,
                                                     float* __restrict__ out_d)
{
    int n = blockIdx.x;
    int t = threadIdx.x;
    float h = bf2f(h1b[(size_t)n * C1 + t]);
    float s = h * asrc[t];
    float d = h * adst[t];
    #pragma unroll
    for (int off = 32; off > 0; off >>= 1) {
        s += __shfl_down(s, off);
        d += __shfl_down(d, off);
    }
    if ((t & 63) == 0) {
        out_s[n * HEADS + (t >> 6)] = s;
        out_d[n * HEADS + (t >> 6)] = d;
    }
}

// ---------- per-node attention halves, layer 2 (bf16 h2) ----------
__global__ __launch_bounds__(64) void alpha2_kernel(const ushort_t* __restrict__ h2b,
                                                    const float* __restrict__ asrc,
                                                    const float* __restrict__ adst,
                                                    float* __restrict__ out_s,
                                                    float* __restrict__ out_d)
{
    int n = blockIdx.x;
    int t = threadIdx.x;
    float a = bf2f(h2b[(size_t)n * C2 + t]);
    float b = bf2f(h2b[(size_t)n * C2 + t + 64]);
    float s = a * asrc[t] + b * asrc[t + 64];
    float d = a * adst[t] + b * adst[t + 64];
    #pragma unroll
    for (int off = 32; off > 0; off >>= 1) {
        s += __shfl_down(s, off);
        d += __shfl_down(d, off);
    }
    if (t == 0) { out_s[n] = s; out_d[n] = d; }
}

// ---------- CSR build ----------
__global__ __launch_bounds__(256) void deg_kernel(const int* __restrict__ ei,
                                                  int* __restrict__ deg)
{
    int e = blockIdx.x * blockDim.x + threadIdx.x;
    if (e >= ETOT) return;
    int s, d; edge_sd(ei, e, s, d);
    atomicAdd(&deg[d], 1);
}

// 4 elems/thread + wave shfl scan.
#define SCAN_T 1024
__global__ __launch_bounds__(SCAN_T) void scan_kernel(const int* __restrict__ deg,
                                                      int* __restrict__ rowptr)
{
    __shared__ int wsum[16];
    __shared__ int chunk_tot;
    __shared__ int carry_s;
    const int t = threadIdx.x, lane = t & 63, w = t >> 6;
    if (t == 0) carry_s = 0;
    __syncthreads();
    for (int base = 0; base < NNODES; base += SCAN_T * 4) {
        int idx = base + t * 4;
        int v0 = (idx + 0 < NNODES) ? deg[idx + 0] : 0;
        int v1 = (idx + 1 < NNODES) ? deg[idx + 1] : 0;
        int v2 = (idx + 2 < NNODES) ? deg[idx + 2] : 0;
        int v3 = (idx + 3 < NNODES) ? deg[idx + 3] : 0;
        int p0 = v0, p1 = p0 + v1, p2 = p1 + v2, p3 = p2 + v3;
        int incl = p3;
        #pragma unroll
        for (int off = 1; off < 64; off <<= 1) {
            int nb = __shfl_up(incl, off);
            if (lane >= off) incl += nb;
        }
        if (lane == 63) wsum[w] = incl;
        __syncthreads();
        if (w == 0 && lane < 16) {
            int ws = wsum[lane];
            int wincl = ws;
            #pragma unroll
            for (int off = 1; off < 16; off <<= 1) {
                int nb = __shfl_up(wincl, off);
                if (lane >= off) wincl += nb;
            }
            wsum[lane] = wincl - ws;            // exclusive
            if (lane == 15) chunk_tot = wincl;
        }
        __syncthreads();
        int carry = carry_s;
        int basev = carry + wsum[w] + (incl - p3);
        if (idx + 0 < NNODES) rowptr[idx + 0] = basev;
        if (idx + 1 < NNODES) rowptr[idx + 1] = basev + p0;
        if (idx + 2 < NNODES) rowptr[idx + 2] = basev + p1;
        if (idx + 3 < NNODES) rowptr[idx + 3] = basev + p2;
        __syncthreads();
        if (t == 0) carry_s = carry + chunk_tot;
        __syncthreads();
    }
    if (threadIdx.x == 0) rowptr[NNODES] = carry_s;
}

__global__ __launch_bounds__(256) void scatter_kernel(const int* __restrict__ ei,
                                                      int* __restrict__ cursor,
                                                      int* __restrict__ srcs)
{
    int e = blockIdx.x * blockDim.x + threadIdx.x;
    if (e >= ETOT) return;
    int s, d; edge_sd(ei, e, s, d);
    int pos = atomicAdd(&cursor[d], 1);
    srcs[pos] = s;
}

// ---------- per-edge normalized attention weights, layer 1 (4 heads) ----------
__global__ __launch_bounds__(256) void weights1_kernel(const int* __restrict__ rowptr,
                                                       const int* __restrict__ srcs,
                                                       const float4* __restrict__ as1,
                                                       const float4* __restrict__ ad1,
                                                       float4* __restrict__ wbuf)
{
    int d = blockIdx.x * 4 + (threadIdx.x >> 6);
    if (d >= NNODES) return;
    int lane = threadIdx.x & 63;
    int beg = rowptr[d], end = rowptr[d + 1];
    float4 adv = ad1[d];
    float m0 = -INFINITY, m1 = -INFINITY, m2 = -INFINITY, m3 = -INFINITY;
    for (int i = beg + lane; i < end; i += 64) {
        int s = srcs[i];
        float4 av = as1[s];
        m0 = fmaxf(m0, lrelu(av.x + adv.x));
        m1 = fmaxf(m1, lrelu(av.y + adv.y));
        m2 = fmaxf(m2, lrelu(av.z + adv.z));
        m3 = fmaxf(m3, lrelu(av.w + adv.w));
    }
    #pragma unroll
    for (int off = 32; off > 0; off >>= 1) {
        m0 = fmaxf(m0, __shfl_xor(m0, off));
        m1 = fmaxf(m1, __shfl_xor(m1, off));
        m2 = fmaxf(m2, __shfl_xor(m2, off));
        m3 = fmaxf(m3, __shfl_xor(m3, off));
    }
    float s0 = 0.f, s1 = 0.f, s2 = 0.f, s3 = 0.f;
    for (int i = beg + lane; i < end; i += 64) {
        int s = srcs[i];
        float4 av = as1[s];
        float w0 = expf(lrelu(av.x + adv.x) - m0);
        float w1 = expf(lrelu(av.y + adv.y) - m1);
        float w2 = expf(lrelu(av.z + adv.z) - m2);
        float w3 = expf(lrelu(av.w + adv.w) - m3);
        wbuf[i] = make_float4(w0, w1, w2, w3);
        s0 += w0; s1 += w1; s2 += w2; s3 += w3;
    }
    #pragma unroll
    for (int off = 32; off > 0; off >>= 1) {
        s0 += __shfl_xor(s0, off);
        s1 += __shfl_xor(s1, off);
        s2 += __shfl_xor(s2, off);
        s3 += __shfl_xor(s3, off);
    }
    float i0 = 1.f / (s0 + 1e-16f), i1 = 1.f / (s1 + 1e-16f);
    float i2 = 1.f / (s2 + 1e-16f), i3 = 1.f / (s3 + 1e-16f);
    for (int i = beg + lane; i < end; i += 64) {
        float4 wv = wbuf[i];
        wbuf[i] = make_float4(wv.x * i0, wv.y * i1, wv.z * i2, wv.w * i3);
    }
}

// ---------- per-edge normalized attention weights, layer 2 (1 head) ----------
__global__ __launch_bounds__(256) void weights2_kernel(const int* __restrict__ rowptr,
                                                       const int* __restrict__ srcs,
                                                       const float* __restrict__ as2,
                                                       const float* __restrict__ ad2,
                                                       float* __restrict__ wbuf)
{
    int d = blockIdx.x * 4 + (threadIdx.x >> 6);
    if (d >= NNODES) return;
    int lane = threadIdx.x & 63;
    int beg = rowptr[d], end = rowptr[d + 1];
    float adv = ad2[d];
    float m = -INFINITY;
    for (int i = beg + lane; i < end; i += 64)
        m = fmaxf(m, lrelu(as2[srcs[i]] + adv));
    #pragma unroll
    for (int off = 32; off > 0; off >>= 1) m = fmaxf(m, __shfl_xor(m, off));
    float sm = 0.f;
    for (int i = beg + lane; i < end; i += 64) {
        float w = expf(lrelu(as2[srcs[i]] + adv) - m);
        wbuf[i] = w;
        sm += w;
    }
    #pragma unroll
    for (int off = 32; off > 0; off >>= 1) sm += __shfl_xor(sm, off);
    float inv = 1.f / (sm + 1e-16f);
    for (int i = beg + lane; i < end; i += 64) wbuf[i] *= inv;
}

// ---------- layer-1 aggregation: wave per dst, lane = 4 channels, 4x unrolled ----------
__global__ __launch_bounds__(256) void aggr1_csr(const int* __restrict__ rowptr,
                                                 const int* __restrict__ srcs,
                                                 const ushort_t* __restrict__ h1b,
                                                 const float* __restrict__ wbuf,
                                                 const float* __restrict__ b1,
                                                 ushort_t* __restrict__ out)
{
    int d = blockIdx.x * 4 + (threadIdx.x >> 6);
    if (d >= NNODES) return;
    int lane = threadIdx.x & 63;
    int c0 = lane * 4;                 // channels [c0, c0+4)
    int head = lane >> 4;              // c0>>6
    int beg = rowptr[d], end = rowptr[d + 1];
    float a0 = 0.f, a1 = 0.f, a2 = 0.f, a3 = 0.f;
    int i = beg;
    for (; i + 3 < end; i += 4) {
        int s0 = srcs[i], s1 = srcs[i + 1], s2 = srcs[i + 2], s3 = srcs[i + 3];
        float w0 = wbuf[i * 4 + head],     w1 = wbuf[i * 4 + 4 + head];
        float w2 = wbuf[i * 4 + 8 + head], w3 = wbuf[i * 4 + 12 + head];
        ushort4 v0 = *(const ushort4*)(h1b + (size_t)s0 * C1 + c0);
        ushort4 v1 = *(const ushort4*)(h1b + (size_t)s1 * C1 + c0);
        ushort4 v2 = *(const ushort4*)(h1b + (size_t)s2 * C1 + c0);
        ushort4 v3 = *(const ushort4*)(h1b + (size_t)s3 * C1 + c0);
        a0 = fmaf(w0, bf2f(v0.x), a0); a1 = fmaf(w0, bf2f(v0.y), a1);
        a2 = fmaf(w0, bf2f(v0.z), a2); a3 = fmaf(w0, bf2f(v0.w), a3);
        a0 = fmaf(w1, bf2f(v1.x), a0); a1 = fmaf(w1, bf2f(v1.y), a1);
        a2 = fmaf(w1, bf2f(v1.z), a2); a3 = fmaf(w1, bf2f(v1.w), a3);
        a0 = fmaf(w2, bf2f(v2.x), a0); a1 = fmaf(w2, bf2f(v2.y), a1);
        a2 = fmaf(w2, bf2f(v2.z), a2); a3 = fmaf(w2, bf2f(v2.w), a3);
        a0 = fmaf(w3, bf2f(v3.x), a0); a1 = fmaf(w3, bf2f(v3.y), a1);
        a2 = fmaf(w3, bf2f(v3.z), a2); a3 = fmaf(w3, bf2f(v3.w), a3);
    }
    for (; i < end; ++i) {
        int s0 = srcs[i];
        float w0 = wbuf[i * 4 + head];
        ushort4 v0 = *(const ushort4*)(h1b + (size_t)s0 * C1 + c0);
        a0 = fmaf(w0, bf2f(v0.x), a0); a1 = fmaf(w0, bf2f(v0.y), a1);
        a2 = fmaf(w0, bf2f(v0.z), a2); a3 = fmaf(w0, bf2f(v0.w), a3);
    }
    float4 bv = *(const float4*)(b1 + c0);
    float o0 = a0 + bv.x, o1 = a1 + bv.y, o2 = a2 + bv.z, o3 = a3 + bv.w;
    ushort4 r;
    r.x = f2b(o0 > 0.f ? o0 : (expf(o0) - 1.f));
    r.y = f2b(o1 > 0.f ? o1 : (expf(o1) - 1.f));
    r.z = f2b(o2 > 0.f ? o2 : (expf(o2) - 1.f));
    r.w = f2b(o3 > 0.f ? o3 : (expf(o3) - 1.f));
    *(ushort4*)(out + (size_t)d * C1 + c0) = r;
}

// ---------- layer-2 aggregation: wave per dst, lane = 2 channels (+bias+L2 norm) ----------
__global__ __launch_bounds__(256) void aggr2_csr(const int* __restrict__ rowptr,
                                                 const int* __restrict__ srcs,
                                                 const ushort_t* __restrict__ h2b,
                                                 const float* __restrict__ wbuf,
                                                 const float* __restrict__ b2,
                                                 float* __restrict__ out)
{
    int d = blockIdx.x * 4 + (threadIdx.x >> 6);
    if (d >= NNODES) return;
    int lane = threadIdx.x & 63;
    int c0 = lane * 2;
    int beg = rowptr[d], end = rowptr[d + 1];
    float a0 = 0.f, a1 = 0.f;
    int i = beg;
    for (; i + 3 < end; i += 4) {
        int s0 = srcs[i], s1 = srcs[i + 1], s2 = srcs[i + 2], s3 = srcs[i + 3];
        float w0 = wbuf[i], w1 = wbuf[i + 1], w2 = wbuf[i + 2], w3 = wbuf[i + 3];
        ushort2 v0 = *(const ushort2*)(h2b + (size_t)s0 * C2 + c0);
        ushort2 v1 = *(const ushort2*)(h2b + (size_t)s1 * C2 + c0);
        ushort2 v2 = *(const ushort2*)(h2b + (size_t)s2 * C2 + c0);
        ushort2 v3 = *(const ushort2*)(h2b + (size_t)s3 * C2 + c0);
        a0 = fmaf(w0, bf2f(v0.x), a0); a1 = fmaf(w0, bf2f(v0.y), a1);
        a0 = fmaf(w1, bf2f(v1.x), a0); a1 = fmaf(w1, bf2f(v1.y), a1);
        a0 = fmaf(w2, bf2f(v2.x), a0); a1 = fmaf(w2, bf2f(v2.y), a1);
        a0 = fmaf(w3, bf2f(v3.x), a0); a1 = fmaf(w3, bf2f(v3.y), a1);
    }
    for (; i < end; ++i) {
        float w0 = wbuf[i];
        ushort2 v0 = *(const ushort2*)(h2b + (size_t)srcs[i] * C2 + c0);
        a0 = fmaf(w0, bf2f(v0.x), a0); a1 = fmaf(w0, bf2f(v0.y), a1);
    }
    float2 bv = *(const float2*)(b2 + c0);
    float o0 = a0 + bv.x, o1 = a1 + bv.y;
    float sq = o0 * o0 + o1 * o1;
    #pragma unroll
    for (int off = 32; off > 0; off >>= 1) sq += __shfl_xor(sq, off);
    float inv = 1.0f / fmaxf(sqrtf(sq), 1e-12f);
    float2 r = make_float2(o0 * inv, o1 * inv);
    *(float2*)(out + (size_t)d * C2 + c0) = r;
}

extern "C" void kernel_launch(void* const* d_in, const int* in_sizes, int n_in,
                              void* d_out, int out_size, void* d_ws, size_t ws_size,
                              hipStream_t stream)
{
    const float* x     = (const float*)d_in[0];
    const int*   ei    = (const int*)d_in[1];
    const float* W1    = (const float*)d_in[2];
    const float* asrc1 = (const float*)d_in[3];
    const float* adst1 = (const float*)d_in[4];
    const float* b1    = (const float*)d_in[5];
    const float* W2    = (const float*)d_in[6];
    const float* asrc2 = (const float*)d_in[7];
    const float* adst2 = (const float*)d_in[8];
    const float* b2    = (const float*)d_in[9];
    float* out = (float*)d_out;

    char* ws = (char*)d_ws;
    size_t off = 0;
    auto alloc = [&](size_t nbytes) {
        void* p = ws + off;
        off += (nbytes + 15) & ~(size_t)15;
        return p;
    };
    ushort_t* h1b    = (ushort_t*)alloc((size_t)NNODES * C1 * 2);   // 25.6 MB
    ushort_t* act1b  = (ushort_t*)alloc((size_t)NNODES * C1 * 2);   // 25.6 MB
    ushort_t* h2b    = (ushort_t*)alloc((size_t)NNODES * C2 * 2);   // 12.8 MB
    ushort_t* W1blk  = (ushort_t*)alloc((size_t)C1 * IN_DIM * 2);
    ushort_t* W2blk  = (ushort_t*)alloc((size_t)C2 * C1 * 2);
    float*    as1    = (float*)alloc((size_t)NNODES * HEADS * 4);
    float*    ad1    = (float*)alloc((size_t)NNODES * HEADS * 4);
    float*    as2    = (float*)alloc((size_t)NNODES * 4);
    float*    ad2    = (float*)alloc((size_t)NNODES * 4);
    float*    wbuf1  = (float*)alloc((size_t)ETOT * HEADS * 4);     // 13.6 MB
    float*    wbuf2  = (float*)alloc((size_t)ETOT * 4);             // 3.4 MB
    int*      deg    = (int*)alloc((size_t)NNODES * 4);
    int*      rowptr = (int*)alloc((size_t)(NNODES + 1) * 4);
    int*      cursor = (int*)alloc((size_t)(NNODES + 1) * 4);
    int*      srcs   = (int*)alloc((size_t)ETOT * 4);               // 3.4 MB

    const int eb = (ETOT + 255) / 256;
    const int nb4 = (NNODES + 3) / 4;
    const int rb = (NNODES + 127) / 128;

    // ---- weight prep (blocked bf16 layout) ----
    wtrans_kernel<<<(IN_DIM * C1 + 255) / 256, 256, 0, stream>>>(W1, W1blk, IN_DIM, C1);
    wtrans_kernel<<<(C1 * C2 + 255) / 256, 256, 0, stream>>>(W2, W2blk, C1, C2);

    // ---- CSR build ----
    hipMemsetAsync(deg, 0, (size_t)NNODES * 4, stream);
    deg_kernel<<<eb, 256, 0, stream>>>(ei, deg);
    scan_kernel<<<1, SCAN_T, 0, stream>>>(deg, rowptr);
    hipMemcpyAsync(cursor, rowptr, (size_t)(NNODES + 1) * 4, hipMemcpyDeviceToDevice, stream);
    scatter_kernel<<<eb, 256, 0, stream>>>(ei, cursor, srcs);

    // ---- Layer 1 ----
    dim3 g1(C1 / 128, rb);   // col-block fastest: duplicate A-readers adjacent
    gemm_fb<<<g1, 256, 0, stream>>>(x, W1blk, h1b, NNODES, C1, IN_DIM);
    alpha1_kernel<<<NNODES, 256, 0, stream>>>(h1b, asrc1, adst1, as1, ad1);
    weights1_kernel<<<nb4, 256, 0, stream>>>(rowptr, srcs, (const float4*)as1,
                                             (const float4*)ad1, (float4*)wbuf1);
    aggr1_csr<<<nb4, 256, 0, stream>>>(rowptr, srcs, h1b, wbuf1, b1, act1b);

    // ---- Layer 2 ----
    dim3 g2(C2 / 128, rb);
    gemm_bb<<<g2, 256, 0, stream>>>(act1b, W2blk, h2b, NNODES, C2, C1);
    alpha2_kernel<<<NNODES, 64, 0, stream>>>(h2b, asrc2, adst2, as2, ad2);
    weights2_kernel<<<nb4, 256, 0, stream>>>(rowptr, srcs, as2, ad2, wbuf2);
    aggr2_csr<<<nb4, 256, 0, stream>>>(rowptr, srcs, h2b, wbuf2, b2, out);
}